// Round 3
// baseline (98.353 us; speedup 1.0000x reference)
//
#include <hip/hip_runtime.h>
#include <math.h>

// KF filtered-position windowed loss, collapsed scalar-recurrence form.
// loss = mean_{b, t in [1,T), d} ( kp_t*(z_t - v) + dt*(v - w_t) )^2,
// v <- v + kv_t*(z_t - v), v0 = 0; gains from the batch-independent scalar
// Riccati recursion (q_pos and p0 provably cancel). Chunked t with Lc=16,
// warm-up Wc=12 (state contraction alpha~0.73 -> ~1e-8 loss error vs 7.7e-7
// threshold). Gains fp32-converged by t~48; only chunks t0<64 need exact gains.
//
// Round 3: coalesced loads via LDS staging. Block = 256 thr handles
// (chunk, 128 batches): cooperative float4 global loads in (b,j) order
// (consecutive lanes -> consecutive addresses), LDS [t][b] float2 layout so
// compute lanes (b,d) read conflict-free (2-way broadcast = free). 1024
// blocks, 44.5 KB LDS -> 3 blocks/CU (3 waves/SIMD, up from 2).

namespace {
constexpr int   Tn = 4096;
constexpr float DTc = 0.005f;
constexpr int   Lc = 16;                 // emit length per chunk
constexpr int   Wc = 12;                 // warm-up length
constexpr int   NCHUNK = Tn / Lc;        // 256
constexpr int   NBpb = 128;              // batches per block
constexpr int   TTmax = Lc + Wc;         // 28 tile timesteps
constexpr int   NTRANS_C = 4;            // chunks with t0 < 64: exact gains
constexpr int   GAINS_N = 64;
constexpr float INVC = 1.0f / (512.0f * 4095.0f * 2.0f);
}

__global__ __launch_bounds__(256) void kf_loss_kernel(
    const float* __restrict__ pred,
    const float* __restrict__ targ,
    const float* __restrict__ q_vel,
    const float* __restrict__ r_vel,
    float* __restrict__ out)
{
  __shared__ float2 zt[TTmax * NBpb];    // 28 KB
  __shared__ float2 wt[Lc * NBpb];       // 16 KB
  __shared__ float skp[GAINS_N];
  __shared__ float skv[GAINS_N];
  __shared__ float wpart[4];

  const int tid = threadIdx.x;
  const int bg  = blockIdx.x & 3;        // batch group (128 b each)
  const int c   = blockIdx.x >> 2;       // chunk id
  const int t0  = c * Lc;
  const int TS  = (t0 >= Wc) ? (t0 - Wc) : 0;   // tile start timestep

  const float* basez = pred + (size_t)bg * NBpb * (Tn * 2);
  const float* basew = targ + (size_t)bg * NBpb * (Tn * 2);

  // ---- stage w tile: 128 b x 16 t x 2 d, coalesced float4 -> LDS [t][b]
  {
    const int woff = t0 * 2;
    #pragma unroll
    for (int it = 0; it < 4; ++it) {
      int i = it * 256 + tid;
      int b = i >> 3, j = i & 7;
      const float4 wv = *(const float4*)(basew + (size_t)b * (Tn * 2) + woff + j * 4);
      wt[(2 * j)     * NBpb + b] = make_float2(wv.x, wv.y);
      wt[(2 * j + 1) * NBpb + b] = make_float2(wv.z, wv.w);
    }
  }
  // ---- stage z tile: 128 b x LT t x 2 d (LT = 28, or 16 for chunk 0)
  if (t0 >= Wc) {
    const int zoff = TS * 2;             // multiple of 4: float4-aligned
    #pragma unroll
    for (int it = 0; it < 7; ++it) {
      int i = it * 256 + tid;
      int b = (int)((unsigned)i / 14u), j = i - b * 14;
      const float4 zv = *(const float4*)(basez + (size_t)b * (Tn * 2) + zoff + j * 4);
      zt[(2 * j)     * NBpb + b] = make_float2(zv.x, zv.y);
      zt[(2 * j + 1) * NBpb + b] = make_float2(zv.z, zv.w);
    }
  } else {
    #pragma unroll
    for (int it = 0; it < 4; ++it) {
      int i = it * 256 + tid;
      int b = i >> 3, j = i & 7;
      const float4 zv = *(const float4*)(basez + (size_t)b * (Tn * 2) + j * 4);
      zt[(2 * j)     * NBpb + b] = make_float2(zv.x, zv.y);
      zt[(2 * j + 1) * NBpb + b] = make_float2(zv.z, zv.w);
    }
  }
  // ---- exact transient gain sequence (only blocks with t0 < 64 use it)
  if (c < NTRANS_C && tid == 0) {
    float bcov = 0.0f, ccov = 1.0f;      // P0 = I -> b=0, c=1
    for (int t = 0; t < GAINS_N; ++t) {
      float bp = fmaf(DTc, ccov, bcov);
      float cp = ccov + q_vel[0];
      float inv = 1.0f / (cp + r_vel[0]);
      float kp = bp * inv;
      float kv = cp * inv;
      skp[t] = kp;  skv[t] = kv;
      bcov = fmaf(-kp, cp, bp);
      ccov = fmaf(-kv, cp, cp);
    }
  }
  __syncthreads();

  // ---- compute: thread (b = tid>>1, d = tid&1) runs one scalar chain
  const int b = tid >> 1, d = tid & 1;
  const float* zf = ((const float*)zt) + d;
  const float* wf = ((const float*)wt) + d;
  float acc = 0.0f;

  if (c >= NTRANS_C) {
    // steady-state gains, closed form (Riccati fixed point)
    const float qv = q_vel[0], r = r_vel[0];
    float u   = 0.5f * (qv + sqrtf(fmaf(qv, qv, 4.0f * qv * r)));
    float inv = 1.0f / (u + r);
    float kv  = u * inv;
    float cst = u - qv;
    float bst = (DTc * cst * r) / u;
    float kp  = (bst + DTc * cst) * inv;

    float v = 0.0f;
    #pragma unroll
    for (int lt = 0; lt < Wc; ++lt)
      v = fmaf(kv, zf[2 * (lt * NBpb + b)] - v, v);
    #pragma unroll
    for (int lt = Wc; lt < TTmax; ++lt) {
      float z = zf[2 * (lt * NBpb + b)];
      float w = wf[2 * ((lt - Wc) * NBpb + b)];
      float innov = z - v;
      float e = fmaf(kp, innov, DTc * (v - w));
      acc = fmaf(e, e, acc);
      v = fmaf(kv, innov, v);
    }
  } else {
    const int warm = t0 - TS;            // 0 (chunk 0) or 12
    float v = 0.0f;
    for (int lt = 0; lt < warm; ++lt) {
      int t = TS + lt;
      v = fmaf(skv[t], zf[2 * (lt * NBpb + b)] - v, v);
    }
    for (int lt = warm; lt < warm + Lc; ++lt) {
      int t = TS + lt;
      float z = zf[2 * (lt * NBpb + b)];
      float innov = z - v;
      if (t > 0) {
        float w = wf[2 * ((lt - warm) * NBpb + b)];
        float e = fmaf(skp[t], innov, DTc * (v - w));
        acc = fmaf(e, e, acc);
      }
      v = fmaf(skv[t], innov, v);
    }
  }

  // ---- block reduction (4 waves), one scaled atomic per block
  #pragma unroll
  for (int off = 32; off > 0; off >>= 1)
    acc += __shfl_down(acc, off);
  const int lane = tid & 63, wid = tid >> 6;
  if (lane == 0) wpart[wid] = acc;
  __syncthreads();
  if (tid == 0) {
    float s = (wpart[0] + wpart[1]) + (wpart[2] + wpart[3]);
    atomicAdd(out, s * INVC);
  }
}

extern "C" void kernel_launch(void* const* d_in, const int* in_sizes, int n_in,
                              void* d_out, int out_size, void* d_ws, size_t ws_size,
                              hipStream_t stream) {
  // inputs: 0 pred_vel (B,T,2) f32, 1 targ_vel (B,T,2) f32,
  //         2 q_pos (unused), 3 q_vel, 4 r_vel, 5 p0 (unused)
  const float* pred = (const float*)d_in[0];
  const float* targ = (const float*)d_in[1];
  const float* qv   = (const float*)d_in[3];
  const float* rv   = (const float*)d_in[4];
  float* out = (float*)d_out;

  hipMemsetAsync(out, 0, sizeof(float), stream);  // d_out is poisoned 0xAA

  dim3 grid(NCHUNK * 4);   // (chunk, batch-group)
  dim3 block(256);
  kf_loss_kernel<<<grid, block, 0, stream>>>(pred, targ, qv, rv, out);
}